// Round 6
// baseline (661.521 us; speedup 1.0000x reference)
//
#include <hip/hip_runtime.h>

namespace {

constexpr int NB = 32, NL = 1024, NC = 128, NP = 96, KW = 5;
constexpr float INV_SQRT2 = 0.70710678118654752440f;

typedef unsigned short u16;
typedef __attribute__((ext_vector_type(4))) u16 u16x4;
typedef __attribute__((ext_vector_type(8))) u16 u16x8;
typedef __attribute__((ext_vector_type(8))) short short8;
typedef __attribute__((ext_vector_type(4))) float f32x4;

__device__ inline u16 f2bf(float f) {
  unsigned u = __float_as_uint(f);
  u += 0x7fff + ((u >> 16) & 1);
  return (u16)(u >> 16);
}

__device__ inline float ftanh(float x) {
  float e = __expf(2.f * x);
  return 1.f - 2.f / (e + 1.f);
}

// ---------------- stats stage 1 ----------------
__global__ void stats1(const float* __restrict__ x, const float* __restrict__ mask,
                       float* __restrict__ part) {
  int b = blockIdx.x, s = blockIdx.y;
  int tid = threadIdx.x;
  int c = tid & 127, lh = tid >> 7;
  const float* xb = x + (size_t)b * NL * NC;
  const float* mb = mask + (size_t)b * NL * NC;
  float s_all = 0.f, d1 = 0.f, sm = 0.f, sm2 = 0.f, cnz = 0.f;
#pragma unroll 4
  for (int i = 0; i < 32; ++i) {
    int l = s * 64 + lh + 2 * i;
    float v = xb[(size_t)l * NC + c];
    float m = mb[(size_t)l * NC + c];
    s_all += v;
    d1 += (m == 1.f) ? 1.f : 0.f;
    bool nz = (m != 0.f);
    float vm = nz ? v : 0.f;
    sm += vm;
    sm2 += vm * v;
    cnz += nz ? 1.f : 0.f;
  }
  __shared__ float red[5][256];
  red[0][tid] = s_all; red[1][tid] = d1; red[2][tid] = sm;
  red[3][tid] = sm2;   red[4][tid] = cnz;
  __syncthreads();
  if (lh == 0) {
    float* pp = part + ((size_t)(b * 16 + s) * 5) * NC + c;
#pragma unroll
    for (int q = 0; q < 5; ++q) pp[q * NC] = red[q][c] + red[q][c + 128];
  }
}

__global__ void stats2(const float* __restrict__ part, float* __restrict__ means,
                       float* __restrict__ stdev) {
  int b = blockIdx.x, c = threadIdx.x;
  float s_all = 0.f, d1 = 0.f, sm = 0.f, sm2 = 0.f, cnz = 0.f;
  for (int s = 0; s < 16; ++s) {
    const float* pp = part + ((size_t)(b * 16 + s) * 5) * NC + c;
    s_all += pp[0];
    d1    += pp[NC];
    sm    += pp[2 * NC];
    sm2   += pp[3 * NC];
    cnz   += pp[4 * NC];
  }
  float mn = s_all / d1;
  float varsum = sm2 - 2.f * mn * sm + mn * mn * cnz;
  means[b * NC + c] = mn;
  stdev[b * NC + c] = sqrtf(varsum / d1 + 1e-5f);
}

// ---------------- normalize + transpose (B,L,C) -> (B,C,L) ----------------
__global__ void norm_transpose(const float* __restrict__ x, const float* __restrict__ mask,
                               const float* __restrict__ means, const float* __restrict__ stdev,
                               float* __restrict__ xt) {
  __shared__ float tile[32][33];
  int b = blockIdx.x;
  int l0 = blockIdx.y * 32;
  int c0 = blockIdx.z * 32;
  int tx = threadIdx.x;
  int ty = threadIdx.y;
  for (int i = ty; i < 32; i += 8) {
    int l = l0 + i, c = c0 + tx;
    float v = x[((size_t)b * NL + l) * NC + c];
    float m = mask[((size_t)b * NL + l) * NC + c];
    float val = (m == 0.f) ? 0.f : (v - means[b * NC + c]);
    tile[i][tx] = val / stdev[b * NC + c];
  }
  __syncthreads();
  for (int i = ty; i < 32; i += 8) {
    xt[((size_t)b * NC + c0 + i) * NL + l0 + tx] = tile[tx][i];
  }
}

// ---------------- Haar transform per row, bf16 out ----------------
__global__ void haar_kernel(const float* __restrict__ xt, u16* __restrict__ freqb) {
  int row = blockIdx.x;
  __shared__ float h[1024], t2[512];
  const float* src = xt + (size_t)row * NL;
  u16* dst = freqb + (size_t)row * NL;
  for (int i = threadIdx.x; i < 1024; i += 256) h[i] = src[i];
  __syncthreads();
  int n = 1024;
  while (n > 1) {
    int half = n >> 1;
    for (int i = threadIdx.x; i < half; i += 256) {
      float e = h[2 * i], o = h[2 * i + 1];
      dst[half + i] = f2bf((e - o) * INV_SQRT2);
      t2[i] = (e + o) * INV_SQRT2;
    }
    __syncthreads();
    for (int i = threadIdx.x; i < half; i += 256) h[i] = t2[i];
    __syncthreads();
    n = half;
  }
  if (threadIdx.x == 0) dst[0] = f2bf(h[0]);
}

// ---------------- f32 -> bf16 ----------------
__global__ void cvt_bf16(const float* __restrict__ in, u16* __restrict__ outp, int n4) {
  int i = blockIdx.x * 256 + threadIdx.x;
  if (i < n4) {
    const float4 v = *reinterpret_cast<const float4*>(in + (size_t)i * 4);
    u16x4 o;
    o.x = f2bf(v.x); o.y = f2bf(v.y); o.z = f2bf(v.z); o.w = f2bf(v.w);
    *reinterpret_cast<u16x4*>(outp + (size_t)i * 4) = o;
  }
}

// ---------------- pack conv weights [60][co][ci][k] -> [60][k][co][ci] bf16 ----------------
__global__ void pack_w(const float* __restrict__ w, u16* __restrict__ wp) {
  int idx = blockIdx.x * 256 + threadIdx.x;
  if (idx >= 60 * 128 * 128) return;
  int ci = idx & 127;
  int co = (idx >> 7) & 127;
  int n = idx >> 14;
  const float* src = w + (size_t)idx * 5;
  size_t base = (size_t)n * (5 * 128 * 128) + (size_t)co * 128 + ci;
#pragma unroll
  for (int k = 0; k < 5; ++k)
    wp[base + (size_t)k * 16384] = f2bf(src[k]);
}

// ---------------- bf16 MFMA GEMM NT, tile 128m x 64n x 64k ----------------
template <int EPI>
__global__ __launch_bounds__(256) void gemm_mfma(const u16* __restrict__ A,
                                                 const u16* __restrict__ Bw,
                                                 u16* __restrict__ Cb, float* __restrict__ Cf,
                                                 int M, int N, int K) {
  __shared__ __align__(16) char sAB[(128 + 64) * 128];
  int m0 = blockIdx.y * 128, n0 = blockIdx.x * 64;
  int tid = threadIdx.x;
  int lane = tid & 63, wv = tid >> 6;
  int wm = (wv >> 1) * 64, wn = (wv & 1) * 32;
  int lg = lane >> 4, l15 = lane & 15;
  f32x4 zero = {0.f, 0.f, 0.f, 0.f};
  f32x4 acc[4][2];
#pragma unroll
  for (int i = 0; i < 4; ++i)
#pragma unroll
    for (int j = 0; j < 2; ++j) acc[i][j] = zero;

  for (int k0 = 0; k0 < K; k0 += 64) {
    __syncthreads();
#pragma unroll
    for (int pass = 0; pass < 6; ++pass) {
      int o = pass * 4096 + tid * 16;
      int cb = o & 127;
      int row;
      const u16* srcp;
      if (pass < 4) {
        row = o >> 7;
        srcp = A + (size_t)(m0 + row) * K + k0 + (cb >> 1);
      } else {
        int rb = (o - 16384) >> 7;
        row = 128 + rb;
        srcp = Bw + (size_t)(n0 + rb) * K + k0 + (cb >> 1);
      }
      int sw = row * 128 + (cb ^ ((row & 7) << 4));
      *(u16x8*)(sAB + sw) = *(const u16x8*)srcp;
    }
    __syncthreads();
#pragma unroll
    for (int ks = 0; ks < 2; ++ks) {
      int kb = ks * 64 + lg * 16;
      short8 a[4], bbf[2];
#pragma unroll
      for (int mt = 0; mt < 4; ++mt) {
        int rr = wm + mt * 16 + l15;
        a[mt] = *(const short8*)(sAB + rr * 128 + (kb ^ ((rr & 7) << 4)));
      }
#pragma unroll
      for (int nt = 0; nt < 2; ++nt) {
        int rr = 128 + wn + nt * 16 + l15;
        bbf[nt] = *(const short8*)(sAB + rr * 128 + (kb ^ ((rr & 7) << 4)));
      }
#pragma unroll
      for (int mt = 0; mt < 4; ++mt)
#pragma unroll
        for (int nt = 0; nt < 2; ++nt)
          acc[mt][nt] = __builtin_amdgcn_mfma_f32_16x16x32_bf16(a[mt], bbf[nt], acc[mt][nt], 0, 0, 0);
    }
  }
#pragma unroll
  for (int mt = 0; mt < 4; ++mt)
#pragma unroll
    for (int nt = 0; nt < 2; ++nt)
#pragma unroll
      for (int r = 0; r < 4; ++r) {
        int row = m0 + wm + mt * 16 + lg * 4 + r;
        int col = n0 + wn + nt * 16 + l15;
        float v = acc[mt][nt][r];
        if (EPI == 0) {
          v = v > 0.f ? v : 0.f;
          Cb[(size_t)row * N + col] = f2bf(v);
        } else {
          Cf[(size_t)row * N + col] = 1.f / (1.f + __expf(-v));
        }
      }
}

// ---------------- fused LayerNorm + combine: xt = xt * LN(lr) + pe ----------------
__global__ void ln_combine(const float* __restrict__ lr, float* __restrict__ xt,
                           const float* __restrict__ g, const float* __restrict__ bta) {
  int row = blockIdx.x;          // b*NC + c
  int c = row & 127;
  const float* p = lr + (size_t)row * 1024;
  int tid = threadIdx.x;
  float v[4];
#pragma unroll
  for (int i = 0; i < 4; ++i) v[i] = p[tid + 256 * i];
  __shared__ float red[256];
  red[tid] = v[0] + v[1] + v[2] + v[3];
  __syncthreads();
  for (int off = 128; off > 0; off >>= 1) {
    if (tid < off) red[tid] += red[tid + off];
    __syncthreads();
  }
  float mu = red[0] * (1.f / 1024.f);
  __syncthreads();
  float sq = 0.f;
#pragma unroll
  for (int i = 0; i < 4; ++i) { float d = v[i] - mu; sq += d * d; }
  red[tid] = sq;
  __syncthreads();
  for (int off = 128; off > 0; off >>= 1) {
    if (tid < off) red[tid] += red[tid + off];
    __syncthreads();
  }
  float rs = rsqrtf(red[0] * (1.f / 1024.f) + 1e-6f);
  int t = c & 63;
  float inv = __expf(-0.14619589f * (float)t);
  float* xr = xt + (size_t)row * 1024;
#pragma unroll
  for (int i = 0; i < 4; ++i) {
    int l = tid + 256 * i;
    float lrv = (v[i] - mu) * rs * g[l] + bta[l];
    float st = (float)l * inv;
    float pe = (c < 64) ? sinf(st) : cosf(st);
    xr[l] = xr[l] * lrv + pe;
  }
}

// ================= fused CIL node: 4 ccbs, 8 waves (2 ccbs in parallel) =================
constexpr size_t SEGc = (size_t)NB * NC;
constexpr int TT = 32;

// conv over 5 taps: acc[mt][nt] (co = wv4*32+mt*16+..., row = nt*16+l15) from
// bf16 LDS tile (256B rows, 16B-granule XOR swizzle) and packed weights [k][co][ci].
template <int NT>
__device__ __forceinline__ void conv_mfma(const char* Sb, const u16* W, const float* Bp,
                                          int wv4, int lg, int l15, f32x4 (&acc)[2][NT]) {
#pragma unroll
  for (int mt = 0; mt < 2; ++mt) {
    const f32x4 bv = *(const f32x4*)(Bp + wv4 * 32 + mt * 16 + lg * 4);
#pragma unroll
    for (int nt = 0; nt < NT; ++nt) acc[mt][nt] = bv;
  }
#pragma unroll
  for (int k = 0; k < 5; ++k) {
#pragma unroll
    for (int cig = 0; cig < 4; ++cig) {
      int ci0 = cig * 32 + lg * 8;
      short8 a[2], bb[NT];
#pragma unroll
      for (int mt = 0; mt < 2; ++mt) {
        int co = wv4 * 32 + mt * 16 + l15;
        a[mt] = *(const short8*)(W + ((size_t)(k * 128 + co) * 128 + ci0));
      }
      int cbyte = 2 * ci0;
#pragma unroll
      for (int nt = 0; nt < NT; ++nt) {
        int i = nt * 16 + l15 + k;
        bb[nt] = *(const short8*)(Sb + i * 256 + (cbyte ^ ((i & 15) << 4)));
      }
#pragma unroll
      for (int mt = 0; mt < 2; ++mt)
#pragma unroll
        for (int nt = 0; nt < NT; ++nt)
          acc[mt][nt] = __builtin_amdgcn_mfma_f32_16x16x32_bf16(a[mt], bb[nt], acc[mt][nt], 0, 0, 0);
    }
  }
}

template <int NT>
__device__ __forceinline__ void write_mid_leaky(char* D, f32x4 (&acc)[2][NT],
                                                int wv4, int lg, int l15) {
#pragma unroll
  for (int mt = 0; mt < 2; ++mt)
#pragma unroll
    for (int nt = 0; nt < NT; ++nt) {
      int j = nt * 16 + l15;
      int co0 = wv4 * 32 + mt * 16 + lg * 4;
      u16x4 m;
#pragma unroll
      for (int r = 0; r < 4; ++r) {
        float v = acc[mt][nt][r];
        v = v > 0.f ? v : 0.01f * v;
        m[r] = f2bf(v);
      }
      *(u16x4*)(D + j * 256 + ((2 * co0) ^ ((j & 15) << 4))) = m;
    }
}

// LDS: S0,S1,S2 bf16 tiles (52 rows x 256B), XEF/XOF fp32 [40][130]
// S0: xe_bf -> midB -> xot_bf -> midD ; S1: xo_bf -> xet_bf ; S2: midA -> midC
__global__ __launch_bounds__(512, 4) void fused_cil(const float* __restrict__ src,
                                                    float* __restrict__ dst,
                                                    const u16* __restrict__ wp1,
                                                    const u16* __restrict__ wp2,
                                                    const float* __restrict__ b1,
                                                    const float* __restrict__ b2,
                                                    int d, int Tn) {
  __shared__ __align__(16) char sm[81536];
  char* S0 = sm;
  char* S1 = sm + 13312;
  char* S2 = sm + 26624;
  float* XEF = (float*)(sm + 39936);
  float* XOF = (float*)(sm + 60736);

  int b = blockIdx.x;
  int t0 = blockIdx.y * TT;
  int p = blockIdx.z;
  // preorder node index of (depth d, BFS pos p)
  int node = 0;
  for (int i2 = d - 1; i2 >= 0; --i2) {
    int bit = (p >> i2) & 1;
    int dd = d - 1 - i2;
    node += 1 + bit * ((1 << (3 - dd)) - 1);
  }
  const size_t WSZ = 5 * 128 * 128;

  int tid = threadIdx.x;
  int TW = 2 * Tn;
  const float* inb = src + ((size_t)p * SEGc + (size_t)b * NC) * TW;

  // ---- stage parent: 52 rows (tau = t0-8+i, clamped), both parities ----
  {
    int i = tid & 63;
    int wq = tid >> 6;  // 0..7
    if (i < 52) {
      int t = t0 - 8 + i;
      t = t < 0 ? 0 : (t >= Tn ? Tn - 1 : t);
      bool fr = (i >= 4) && (i < 44);
      const float* rowp = inb + 2 * t;
      int sw0 = (i & 15) << 4;
#pragma unroll
      for (int pp = 0; pp < 8; ++pp) {
        int pr = wq * 8 + pp;
        float2 v0 = *(const float2*)(rowp + (size_t)(2 * pr) * TW);
        float2 v1 = *(const float2*)(rowp + (size_t)(2 * pr + 1) * TW);
        unsigned pe = (unsigned)f2bf(v0.x) | ((unsigned)f2bf(v1.x) << 16);
        unsigned po = (unsigned)f2bf(v0.y) | ((unsigned)f2bf(v1.y) << 16);
        int sw = (4 * pr) ^ sw0;
        *(unsigned*)(S0 + i * 256 + sw) = pe;
        *(unsigned*)(S1 + i * 256 + sw) = po;
        if (fr) {
          *(float2*)(XEF + (i - 4) * 130 + 2 * pr) = make_float2(v0.x, v1.x);
          *(float2*)(XOF + (i - 4) * 130 + 2 * pr) = make_float2(v0.y, v1.y);
        }
      }
    }
  }
  __syncthreads();  // B1

  int lane = tid & 63, wv = tid >> 6;
  int grp = wv >> 2;      // 0: ccb0/ccb2 ; 1: ccb1/ccb3
  int wv4 = wv & 3;
  int lg = lane >> 4, l15 = lane & 15;
  int co_base = wv4 * 32 + lg * 4;

  int wi1 = node * 4 + grp;       // conv weights for phase-A (ccb0 / ccb1)
  int wi2 = node * 4 + 2 + grp;   // phase-B (ccb2 / ccb3)
  const u16* W1A = wp1 + (size_t)wi1 * WSZ;
  const u16* W2A = wp2 + (size_t)wi1 * WSZ;
  const float* B1A = b1 + (size_t)wi1 * 128;
  const float* B2A = b2 + (size_t)wi1 * 128;
  const u16* W1B = wp1 + (size_t)wi2 * WSZ;
  const u16* W2B = wp2 + (size_t)wi2 * WSZ;
  const float* B1B = b1 + (size_t)wi2 * 128;
  const float* B2B = b2 + (size_t)wi2 * 128;

  // ---- phase A conv1: G0 on xo (S1), G1 on xe (S0) ----
  {
    f32x4 acc1[2][3];
    conv_mfma<3>(grp ? S0 : S1, W1A, B1A, wv4, lg, l15, acc1);
    __syncthreads();  // B2: parent tile reads complete
    write_mid_leaky<3>(grp ? S0 : S2, acc1, wv4, lg, l15);  // midA->S2, midB->S0
  }
  __syncthreads();  // B3

  // ---- phase A conv2 + combine: xet = xe*exp(tanh) (G0, XEF), xot (G1, XOF) ----
  u16x4 sx[2][3];
  {
    f32x4 acc2[2][3];
    conv_mfma<3>(grp ? S0 : S2, W2A, B2A, wv4, lg, l15, acc2);
    float* XF = grp ? XOF : XEF;
#pragma unroll
    for (int mt = 0; mt < 2; ++mt)
#pragma unroll
      for (int nt = 0; nt < 3; ++nt) {
        int jx = nt * 16 + l15;
        if (jx < 40) {
          int co0 = co_base + mt * 16;
          float* rowf = XF + jx * 130 + co0;
          float2 a01 = *(float2*)rowf;
          float2 a23 = *(float2*)(rowf + 2);
          float xv[4] = {a01.x, a01.y, a23.x, a23.y};
          u16x4 mb;
#pragma unroll
          for (int r = 0; r < 4; ++r) {
            float res = xv[r] * __expf(ftanh(acc2[mt][nt][r]));
            rowf[r] = res;
            mb[r] = f2bf(res);
          }
          sx[mt][nt] = mb;
        }
      }
  }
  __syncthreads();  // B4: mid reads done, XEF/XOF stable

  // ---- write xet_bf -> S1 (G0), xot_bf -> S0 (G1), with edge-pad fold ----
  {
    char* DX = grp ? S0 : S1;
#pragma unroll
    for (int mt = 0; mt < 2; ++mt)
#pragma unroll
      for (int nt = 0; nt < 3; ++nt) {
        int jx = nt * 16 + l15;
        if (jx < 40) {
          int co0 = co_base + mt * 16;
          int cb = (2 * co0);
          *(u16x4*)(DX + jx * 256 + (cb ^ ((jx & 15) << 4))) = sx[mt][nt];
          if (t0 == 0 && jx == 4) {
#pragma unroll
            for (int rr = 0; rr < 4; ++rr)
              *(u16x4*)(DX + rr * 256 + (cb ^ ((rr & 15) << 4))) = sx[mt][nt];
          }
          if (t0 == Tn - TT && jx == 35) {
#pragma unroll
            for (int rr = 36; rr < 40; ++rr)
              *(u16x4*)(DX + rr * 256 + (cb ^ ((rr & 15) << 4))) = sx[mt][nt];
          }
        }
      }
  }
  __syncthreads();  // B5

  // ---- phase B conv1: G0 on xot (S0), G1 on xet (S1) ----
  {
    f32x4 acc1[2][3];
    conv_mfma<3>(grp ? S1 : S0, W1B, B1B, wv4, lg, l15, acc1);
    __syncthreads();  // B6: xet/xot tile reads complete
    write_mid_leaky<3>(grp ? S0 : S2, acc1, wv4, lg, l15);  // midC->S2, midD->S0
  }
  __syncthreads();  // B7

  // ---- phase B conv2 + final combine + store ----
  {
    f32x4 acc2[2][2];
    conv_mfma<2>(grp ? S0 : S2, W2B, B2B, wv4, lg, l15, acc2);
    float* outb = dst + ((size_t)(2 * p + grp) * SEGc + (size_t)b * NC) * Tn;
    const float* XF = grp ? XOF : XEF;
#pragma unroll
    for (int mt = 0; mt < 2; ++mt)
#pragma unroll
      for (int nt = 0; nt < 2; ++nt) {
        int tl = nt * 16 + l15;
        int co0 = co_base + mt * 16;
        const float* xrow = XF + (tl + 4) * 130 + co0;
#pragma unroll
        for (int r = 0; r < 4; ++r) {
          float tv = ftanh(acc2[mt][nt][r]);
          float res = grp ? (xrow[r] - tv) : (xrow[r] + tv);
          outb[(size_t)(co0 + r) * Tn + t0 + tl] = res;
        }
      }
  }
}

// ---------------- final projection + denorm (gathers leaf layout) ----------------
__global__ void final_kernel(const float* __restrict__ dect, const float* __restrict__ xt,
                             const float* __restrict__ projw, const float* __restrict__ means,
                             const float* __restrict__ stdev, float* __restrict__ out) {
  int b = blockIdx.x, p = blockIdx.y;
  int tid = threadIdx.x;
  const float* w = projw + (size_t)(1024 + p) * 1024;
  const float* x0 = xt + (size_t)b * NC * NL;
  float a[3] = {0.f, 0.f, 0.f};
  for (int l = tid; l < 1024; l += 256) {
    float wv = w[l];
    int rl = l & 7;
    int pb = ((rl & 1) << 2) | (rl & 2) | (rl >> 2);
    int br = (l >> 3) & 1;
    int t = l >> 4;
    const float* dl = dect + ((size_t)(2 * pb + br) * NB + b) * NC * 64 + t;
#pragma unroll
    for (int cc = 0; cc < 3; ++cc)
      a[cc] += wv * (dl[(size_t)cc * 64] + x0[(size_t)cc * NL + l]);
  }
  __shared__ float red[3][256];
  for (int cc = 0; cc < 3; ++cc) red[cc][tid] = a[cc];
  __syncthreads();
  for (int off = 128; off > 0; off >>= 1) {
    if (tid < off) {
      red[0][tid] += red[0][tid + off];
      red[1][tid] += red[1][tid + off];
      red[2][tid] += red[2][tid + off];
    }
    __syncthreads();
  }
  if (tid < 3) {
    out[((size_t)b * NP + p) * 3 + tid] = red[tid][0] * stdev[b * NC + tid] + means[b * NC + tid];
  }
}

}  // namespace

extern "C" void kernel_launch(void* const* d_in, const int* in_sizes, int n_in,
                              void* d_out, int out_size, void* d_ws, size_t ws_size,
                              hipStream_t stream) {
  (void)in_sizes; (void)n_in; (void)out_size; (void)ws_size;
  const float* x_enc = (const float*)d_in[0];
  const float* mask  = (const float*)d_in[1];
  const float* fc1_w = (const float*)d_in[2];
  const float* fc2_w = (const float*)d_in[3];
  const float* ln_g  = (const float*)d_in[4];
  const float* ln_b  = (const float*)d_in[5];
  const float* w1    = (const float*)d_in[6];
  const float* b1    = (const float*)d_in[7];
  const float* w2    = (const float*)d_in[8];
  const float* b2    = (const float*)d_in[9];
  const float* projw = (const float*)d_in[10];
  float* out = (float*)d_out;
  float* ws = (float*)d_ws;

  float* means = ws + 0;          // 4096
  float* stdev = ws + 4096;       // 4096
  float* x_t   = ws + 139264;     // 4,194,304  (B,C,L) fp32, depth-0 parent
  float* freq  = ws + 4333568;    // 4,194,304  lr fp32 -> depth-2 out
  float* IN1   = ws + 8527872;    // 4,194,304  hid_bf -> depth-0 out -> leaf out (dect)
  float* IN2   = ws + 12722176;   // 4,194,304  fc w bf16 -> depth-1 out
  float* xetr  = ws + 16916480;   // freq_bf (bf16)
  float* wp1f  = ws + 21110784;   // stats partials -> packed conv w1 bf16
  float* wp2f  = ws + 23568384;   // packed conv w2 bf16
  float* dect = IN1;
  float* stats_part = wp1f;
  u16* freq_bf = (u16*)xetr;
  u16* hid_bf  = (u16*)IN1;
  u16* fc1w_bf = (u16*)IN2;
  u16* fc2w_bf = (u16*)(IN2 + 1048576);
  u16* wp1 = (u16*)wp1f;
  u16* wp2 = (u16*)wp2f;

  stats1<<<dim3(NB, 16), 256, 0, stream>>>(x_enc, mask, stats_part);
  stats2<<<NB, 128, 0, stream>>>(stats_part, means, stdev);
  norm_transpose<<<dim3(NB, NL / 32, NC / 32), dim3(32, 8), 0, stream>>>(x_enc, mask, means, stdev, x_t);
  haar_kernel<<<NB * NC, 256, 0, stream>>>(x_t, freq_bf);

  cvt_bf16<<<2048, 256, 0, stream>>>(fc1_w, fc1w_bf, 524288);
  cvt_bf16<<<2048, 256, 0, stream>>>(fc2_w, fc2w_bf, 524288);
  pack_w<<<3840, 256, 0, stream>>>(w1, wp1);
  pack_w<<<3840, 256, 0, stream>>>(w2, wp2);

  gemm_mfma<0><<<dim3(32, 32), 256, 0, stream>>>(freq_bf, fc1w_bf, hid_bf, nullptr, 4096, 2048, 1024);
  gemm_mfma<1><<<dim3(16, 32), 256, 0, stream>>>(hid_bf, fc2w_bf, nullptr, freq, 4096, 1024, 2048);

  ln_combine<<<4096, 256, 0, stream>>>(freq, x_t, ln_g, ln_b);

  // tree: 4 fused launches; depth-buffers: x_t -> IN1 -> IN2 -> freq -> IN1(dect)
  float* dbuf[5] = {x_t, IN1, IN2, freq, IN1};
  for (int d = 0; d < 4; ++d) {
    int Tn = 512 >> d;
    dim3 grid(NB, Tn / TT, 1 << d);
    fused_cil<<<grid, 512, 0, stream>>>(dbuf[d], dbuf[d + 1], wp1, wp2, b1, b2, d, Tn);
  }

  final_kernel<<<dim3(NB, NP), 256, 0, stream>>>(dect, x_t, projw, means, stdev, out);
}

// Round 7
// 502.665 us; speedup vs baseline: 1.3160x; 1.3160x over previous
//
#include <hip/hip_runtime.h>

namespace {

constexpr int NB = 32, NL = 1024, NC = 128, NP = 96, KW = 5;
constexpr float INV_SQRT2 = 0.70710678118654752440f;

typedef unsigned short u16;
typedef __attribute__((ext_vector_type(4))) u16 u16x4;
typedef __attribute__((ext_vector_type(8))) u16 u16x8;
typedef __attribute__((ext_vector_type(8))) short short8;
typedef __attribute__((ext_vector_type(4))) float f32x4;

__device__ inline u16 f2bf(float f) {
  unsigned u = __float_as_uint(f);
  u += 0x7fff + ((u >> 16) & 1);
  return (u16)(u >> 16);
}

__device__ inline float ftanh(float x) {
  float e = __expf(2.f * x);
  return 1.f - 2.f / (e + 1.f);
}

// ---------------- stats stage 1 ----------------
__global__ void stats1(const float* __restrict__ x, const float* __restrict__ mask,
                       float* __restrict__ part) {
  int b = blockIdx.x, s = blockIdx.y;
  int tid = threadIdx.x;
  int c = tid & 127, lh = tid >> 7;
  const float* xb = x + (size_t)b * NL * NC;
  const float* mb = mask + (size_t)b * NL * NC;
  float s_all = 0.f, d1 = 0.f, sm = 0.f, sm2 = 0.f, cnz = 0.f;
#pragma unroll 4
  for (int i = 0; i < 32; ++i) {
    int l = s * 64 + lh + 2 * i;
    float v = xb[(size_t)l * NC + c];
    float m = mb[(size_t)l * NC + c];
    s_all += v;
    d1 += (m == 1.f) ? 1.f : 0.f;
    bool nz = (m != 0.f);
    float vm = nz ? v : 0.f;
    sm += vm;
    sm2 += vm * v;
    cnz += nz ? 1.f : 0.f;
  }
  __shared__ float red[5][256];
  red[0][tid] = s_all; red[1][tid] = d1; red[2][tid] = sm;
  red[3][tid] = sm2;   red[4][tid] = cnz;
  __syncthreads();
  if (lh == 0) {
    float* pp = part + ((size_t)(b * 16 + s) * 5) * NC + c;
#pragma unroll
    for (int q = 0; q < 5; ++q) pp[q * NC] = red[q][c] + red[q][c + 128];
  }
}

__global__ void stats2(const float* __restrict__ part, float* __restrict__ means,
                       float* __restrict__ stdev) {
  int b = blockIdx.x, c = threadIdx.x;
  float s_all = 0.f, d1 = 0.f, sm = 0.f, sm2 = 0.f, cnz = 0.f;
  for (int s = 0; s < 16; ++s) {
    const float* pp = part + ((size_t)(b * 16 + s) * 5) * NC + c;
    s_all += pp[0];
    d1    += pp[NC];
    sm    += pp[2 * NC];
    sm2   += pp[3 * NC];
    cnz   += pp[4 * NC];
  }
  float mn = s_all / d1;
  float varsum = sm2 - 2.f * mn * sm + mn * mn * cnz;
  means[b * NC + c] = mn;
  stdev[b * NC + c] = sqrtf(varsum / d1 + 1e-5f);
}

// ---------------- normalize + transpose (B,L,C) -> (B,C,L) ----------------
__global__ void norm_transpose(const float* __restrict__ x, const float* __restrict__ mask,
                               const float* __restrict__ means, const float* __restrict__ stdev,
                               float* __restrict__ xt) {
  __shared__ float tile[32][33];
  int b = blockIdx.x;
  int l0 = blockIdx.y * 32;
  int c0 = blockIdx.z * 32;
  int tx = threadIdx.x;
  int ty = threadIdx.y;
  for (int i = ty; i < 32; i += 8) {
    int l = l0 + i, c = c0 + tx;
    float v = x[((size_t)b * NL + l) * NC + c];
    float m = mask[((size_t)b * NL + l) * NC + c];
    float val = (m == 0.f) ? 0.f : (v - means[b * NC + c]);
    tile[i][tx] = val / stdev[b * NC + c];
  }
  __syncthreads();
  for (int i = ty; i < 32; i += 8) {
    xt[((size_t)b * NC + c0 + i) * NL + l0 + tx] = tile[tx][i];
  }
}

// ---------------- Haar transform per row, bf16 out ----------------
__global__ void haar_kernel(const float* __restrict__ xt, u16* __restrict__ freqb) {
  int row = blockIdx.x;
  __shared__ float h[1024], t2[512];
  const float* src = xt + (size_t)row * NL;
  u16* dst = freqb + (size_t)row * NL;
  for (int i = threadIdx.x; i < 1024; i += 256) h[i] = src[i];
  __syncthreads();
  int n = 1024;
  while (n > 1) {
    int half = n >> 1;
    for (int i = threadIdx.x; i < half; i += 256) {
      float e = h[2 * i], o = h[2 * i + 1];
      dst[half + i] = f2bf((e - o) * INV_SQRT2);
      t2[i] = (e + o) * INV_SQRT2;
    }
    __syncthreads();
    for (int i = threadIdx.x; i < half; i += 256) h[i] = t2[i];
    __syncthreads();
    n = half;
  }
  if (threadIdx.x == 0) dst[0] = f2bf(h[0]);
}

// ---------------- f32 -> bf16 ----------------
__global__ void cvt_bf16(const float* __restrict__ in, u16* __restrict__ outp, int n4) {
  int i = blockIdx.x * 256 + threadIdx.x;
  if (i < n4) {
    const float4 v = *reinterpret_cast<const float4*>(in + (size_t)i * 4);
    u16x4 o;
    o.x = f2bf(v.x); o.y = f2bf(v.y); o.z = f2bf(v.z); o.w = f2bf(v.w);
    *reinterpret_cast<u16x4*>(outp + (size_t)i * 4) = o;
  }
}

// ---------------- pack conv weights [60][co][ci][k] -> [60][k][co][ci] bf16 ----------------
__global__ void pack_w(const float* __restrict__ w, u16* __restrict__ wp) {
  int idx = blockIdx.x * 256 + threadIdx.x;
  if (idx >= 60 * 128 * 128) return;
  int ci = idx & 127;
  int co = (idx >> 7) & 127;
  int n = idx >> 14;
  const float* src = w + (size_t)idx * 5;
  size_t base = (size_t)n * (5 * 128 * 128) + (size_t)co * 128 + ci;
#pragma unroll
  for (int k = 0; k < 5; ++k)
    wp[base + (size_t)k * 16384] = f2bf(src[k]);
}

// ---------------- bf16 MFMA GEMM NT, tile 128m x 64n x 64k ----------------
template <int EPI>
__global__ __launch_bounds__(256) void gemm_mfma(const u16* __restrict__ A,
                                                 const u16* __restrict__ Bw,
                                                 u16* __restrict__ Cb, float* __restrict__ Cf,
                                                 int M, int N, int K) {
  __shared__ __align__(16) char sAB[(128 + 64) * 128];
  int m0 = blockIdx.y * 128, n0 = blockIdx.x * 64;
  int tid = threadIdx.x;
  int lane = tid & 63, wv = tid >> 6;
  int wm = (wv >> 1) * 64, wn = (wv & 1) * 32;
  int lg = lane >> 4, l15 = lane & 15;
  f32x4 zero = {0.f, 0.f, 0.f, 0.f};
  f32x4 acc[4][2];
#pragma unroll
  for (int i = 0; i < 4; ++i)
#pragma unroll
    for (int j = 0; j < 2; ++j) acc[i][j] = zero;

  for (int k0 = 0; k0 < K; k0 += 64) {
    __syncthreads();
#pragma unroll
    for (int pass = 0; pass < 6; ++pass) {
      int o = pass * 4096 + tid * 16;
      int cb = o & 127;
      int row;
      const u16* srcp;
      if (pass < 4) {
        row = o >> 7;
        srcp = A + (size_t)(m0 + row) * K + k0 + (cb >> 1);
      } else {
        int rb = (o - 16384) >> 7;
        row = 128 + rb;
        srcp = Bw + (size_t)(n0 + rb) * K + k0 + (cb >> 1);
      }
      int sw = row * 128 + (cb ^ ((row & 7) << 4));
      *(u16x8*)(sAB + sw) = *(const u16x8*)srcp;
    }
    __syncthreads();
#pragma unroll
    for (int ks = 0; ks < 2; ++ks) {
      int kb = ks * 64 + lg * 16;
      short8 a[4], bbf[2];
#pragma unroll
      for (int mt = 0; mt < 4; ++mt) {
        int rr = wm + mt * 16 + l15;
        a[mt] = *(const short8*)(sAB + rr * 128 + (kb ^ ((rr & 7) << 4)));
      }
#pragma unroll
      for (int nt = 0; nt < 2; ++nt) {
        int rr = 128 + wn + nt * 16 + l15;
        bbf[nt] = *(const short8*)(sAB + rr * 128 + (kb ^ ((rr & 7) << 4)));
      }
#pragma unroll
      for (int mt = 0; mt < 4; ++mt)
#pragma unroll
        for (int nt = 0; nt < 2; ++nt)
          acc[mt][nt] = __builtin_amdgcn_mfma_f32_16x16x32_bf16(a[mt], bbf[nt], acc[mt][nt], 0, 0, 0);
    }
  }
#pragma unroll
  for (int mt = 0; mt < 4; ++mt)
#pragma unroll
    for (int nt = 0; nt < 2; ++nt)
#pragma unroll
      for (int r = 0; r < 4; ++r) {
        int row = m0 + wm + mt * 16 + lg * 4 + r;
        int col = n0 + wn + nt * 16 + l15;
        float v = acc[mt][nt][r];
        if (EPI == 0) {
          v = v > 0.f ? v : 0.f;
          Cb[(size_t)row * N + col] = f2bf(v);
        } else {
          Cf[(size_t)row * N + col] = 1.f / (1.f + __expf(-v));
        }
      }
}

// ---------------- fused LayerNorm + combine: xt = xt * LN(lr) + pe ----------------
__global__ void ln_combine(const float* __restrict__ lr, float* __restrict__ xt,
                           const float* __restrict__ g, const float* __restrict__ bta) {
  int row = blockIdx.x;          // b*NC + c
  int c = row & 127;
  const float* p = lr + (size_t)row * 1024;
  int tid = threadIdx.x;
  float v[4];
#pragma unroll
  for (int i = 0; i < 4; ++i) v[i] = p[tid + 256 * i];
  __shared__ float red[256];
  red[tid] = v[0] + v[1] + v[2] + v[3];
  __syncthreads();
  for (int off = 128; off > 0; off >>= 1) {
    if (tid < off) red[tid] += red[tid + off];
    __syncthreads();
  }
  float mu = red[0] * (1.f / 1024.f);
  __syncthreads();
  float sq = 0.f;
#pragma unroll
  for (int i = 0; i < 4; ++i) { float d = v[i] - mu; sq += d * d; }
  red[tid] = sq;
  __syncthreads();
  for (int off = 128; off > 0; off >>= 1) {
    if (tid < off) red[tid] += red[tid + off];
    __syncthreads();
  }
  float rs = rsqrtf(red[0] * (1.f / 1024.f) + 1e-6f);
  int t = c & 63;
  float inv = __expf(-0.14619589f * (float)t);
  float* xr = xt + (size_t)row * 1024;
#pragma unroll
  for (int i = 0; i < 4; ++i) {
    int l = tid + 256 * i;
    float lrv = (v[i] - mu) * rs * g[l] + bta[l];
    float st = (float)l * inv;
    float pe = (c < 64) ? sinf(st) : cosf(st);
    xr[l] = xr[l] * lrv + pe;
  }
}

// ================= fused CIL node: 4 ccbs, 8 waves (2 ccbs in parallel) =================
constexpr size_t SEGc = (size_t)NB * NC;
constexpr int TT = 32;

// conv over 5 taps: acc[mt][nt] (co = wv4*32+mt*16+..., row = nt*16+l15) from
// bf16 LDS tile (256B rows, 16B-granule XOR swizzle) and packed weights [k][co][ci].
template <int NT>
__device__ __forceinline__ void conv_mfma(const char* Sb, const u16* W, const float* Bp,
                                          int wv4, int lg, int l15, f32x4 (&acc)[2][NT]) {
#pragma unroll
  for (int mt = 0; mt < 2; ++mt) {
    const f32x4 bv = *(const f32x4*)(Bp + wv4 * 32 + mt * 16 + lg * 4);
#pragma unroll
    for (int nt = 0; nt < NT; ++nt) acc[mt][nt] = bv;
  }
#pragma unroll
  for (int k = 0; k < 5; ++k) {
#pragma unroll
    for (int cig = 0; cig < 4; ++cig) {
      int ci0 = cig * 32 + lg * 8;
      short8 a[2], bb[NT];
#pragma unroll
      for (int mt = 0; mt < 2; ++mt) {
        int co = wv4 * 32 + mt * 16 + l15;
        a[mt] = *(const short8*)(W + ((size_t)(k * 128 + co) * 128 + ci0));
      }
      int cbyte = 2 * ci0;
#pragma unroll
      for (int nt = 0; nt < NT; ++nt) {
        int i = nt * 16 + l15 + k;
        bb[nt] = *(const short8*)(Sb + i * 256 + (cbyte ^ ((i & 15) << 4)));
      }
#pragma unroll
      for (int mt = 0; mt < 2; ++mt)
#pragma unroll
        for (int nt = 0; nt < NT; ++nt)
          acc[mt][nt] = __builtin_amdgcn_mfma_f32_16x16x32_bf16(a[mt], bb[nt], acc[mt][nt], 0, 0, 0);
    }
  }
}

template <int NT>
__device__ __forceinline__ void write_mid_leaky(char* D, f32x4 (&acc)[2][NT],
                                                int wv4, int lg, int l15) {
#pragma unroll
  for (int mt = 0; mt < 2; ++mt)
#pragma unroll
    for (int nt = 0; nt < NT; ++nt) {
      int j = nt * 16 + l15;
      int co0 = wv4 * 32 + mt * 16 + lg * 4;
      u16x4 m;
#pragma unroll
      for (int r = 0; r < 4; ++r) {
        float v = acc[mt][nt][r];
        v = v > 0.f ? v : 0.01f * v;
        m[r] = f2bf(v);
      }
      *(u16x4*)(D + j * 256 + ((2 * co0) ^ ((j & 15) << 4))) = m;
    }
}

// LDS: S0,S1,S2 bf16 tiles (52 rows x 256B), XEF/XOF fp32 [40][130]
// S0: xe_bf -> midB -> xot_bf -> midD ; S1: xo_bf -> xet_bf ; S2: midA -> midC
// NOTE launch_bounds: 8-wave block; second arg 2 keeps the VGPR cap >= 128.
// (512,4) capped the allocator at 64 VGPR -> ~170MB/dispatch scratch spill traffic (R5).
__global__ __launch_bounds__(512, 2) void fused_cil(const float* __restrict__ src,
                                                    float* __restrict__ dst,
                                                    const u16* __restrict__ wp1,
                                                    const u16* __restrict__ wp2,
                                                    const float* __restrict__ b1,
                                                    const float* __restrict__ b2,
                                                    int d, int Tn) {
  __shared__ __align__(16) char sm[81536];
  char* S0 = sm;
  char* S1 = sm + 13312;
  char* S2 = sm + 26624;
  float* XEF = (float*)(sm + 39936);
  float* XOF = (float*)(sm + 60736);

  int b = blockIdx.x;
  int t0 = blockIdx.y * TT;
  int p = blockIdx.z;
  // preorder node index of (depth d, BFS pos p)
  int node = 0;
  for (int i2 = d - 1; i2 >= 0; --i2) {
    int bit = (p >> i2) & 1;
    int dd = d - 1 - i2;
    node += 1 + bit * ((1 << (3 - dd)) - 1);
  }
  const size_t WSZ = 5 * 128 * 128;

  int tid = threadIdx.x;
  int TW = 2 * Tn;
  const float* inb = src + ((size_t)p * SEGc + (size_t)b * NC) * TW;

  // ---- stage parent: 52 rows (tau = t0-8+i, clamped), both parities ----
  {
    int i = tid & 63;
    int wq = tid >> 6;  // 0..7
    if (i < 52) {
      int t = t0 - 8 + i;
      t = t < 0 ? 0 : (t >= Tn ? Tn - 1 : t);
      bool fr = (i >= 4) && (i < 44);
      const float* rowp = inb + 2 * t;
      int sw0 = (i & 15) << 4;
#pragma unroll
      for (int pp = 0; pp < 8; ++pp) {
        int pr = wq * 8 + pp;
        float2 v0 = *(const float2*)(rowp + (size_t)(2 * pr) * TW);
        float2 v1 = *(const float2*)(rowp + (size_t)(2 * pr + 1) * TW);
        unsigned pe = (unsigned)f2bf(v0.x) | ((unsigned)f2bf(v1.x) << 16);
        unsigned po = (unsigned)f2bf(v0.y) | ((unsigned)f2bf(v1.y) << 16);
        int sw = (4 * pr) ^ sw0;
        *(unsigned*)(S0 + i * 256 + sw) = pe;
        *(unsigned*)(S1 + i * 256 + sw) = po;
        if (fr) {
          *(float2*)(XEF + (i - 4) * 130 + 2 * pr) = make_float2(v0.x, v1.x);
          *(float2*)(XOF + (i - 4) * 130 + 2 * pr) = make_float2(v0.y, v1.y);
        }
      }
    }
  }
  __syncthreads();  // B1

  int lane = tid & 63, wv = tid >> 6;
  int grp = wv >> 2;      // 0: ccb0/ccb2 ; 1: ccb1/ccb3
  int wv4 = wv & 3;
  int lg = lane >> 4, l15 = lane & 15;
  int co_base = wv4 * 32 + lg * 4;

  int wi1 = node * 4 + grp;       // conv weights for phase-A (ccb0 / ccb1)
  int wi2 = node * 4 + 2 + grp;   // phase-B (ccb2 / ccb3)
  const u16* W1A = wp1 + (size_t)wi1 * WSZ;
  const u16* W2A = wp2 + (size_t)wi1 * WSZ;
  const float* B1A = b1 + (size_t)wi1 * 128;
  const float* B2A = b2 + (size_t)wi1 * 128;
  const u16* W1B = wp1 + (size_t)wi2 * WSZ;
  const u16* W2B = wp2 + (size_t)wi2 * WSZ;
  const float* B1B = b1 + (size_t)wi2 * 128;
  const float* B2B = b2 + (size_t)wi2 * 128;

  // ---- phase A conv1: G0 on xo (S1), G1 on xe (S0) ----
  {
    f32x4 acc1[2][3];
    conv_mfma<3>(grp ? S0 : S1, W1A, B1A, wv4, lg, l15, acc1);
    __syncthreads();  // B2: parent tile reads complete
    write_mid_leaky<3>(grp ? S0 : S2, acc1, wv4, lg, l15);  // midA->S2, midB->S0
  }
  __syncthreads();  // B3

  // ---- phase A conv2 + combine: xet = xe*exp(tanh) (G0, XEF), xot (G1, XOF) ----
  u16x4 sx[2][3];
  {
    f32x4 acc2[2][3];
    conv_mfma<3>(grp ? S0 : S2, W2A, B2A, wv4, lg, l15, acc2);
    float* XF = grp ? XOF : XEF;
#pragma unroll
    for (int mt = 0; mt < 2; ++mt)
#pragma unroll
      for (int nt = 0; nt < 3; ++nt) {
        int jx = nt * 16 + l15;
        if (jx < 40) {
          int co0 = co_base + mt * 16;
          float* rowf = XF + jx * 130 + co0;
          float2 a01 = *(float2*)rowf;
          float2 a23 = *(float2*)(rowf + 2);
          float xv[4] = {a01.x, a01.y, a23.x, a23.y};
          u16x4 mb;
#pragma unroll
          for (int r = 0; r < 4; ++r) {
            float res = xv[r] * __expf(ftanh(acc2[mt][nt][r]));
            rowf[r] = res;
            mb[r] = f2bf(res);
          }
          sx[mt][nt] = mb;
        }
      }
  }
  __syncthreads();  // B4: mid reads done, XEF/XOF stable

  // ---- write xet_bf -> S1 (G0), xot_bf -> S0 (G1), with edge-pad fold ----
  {
    char* DX = grp ? S0 : S1;
#pragma unroll
    for (int mt = 0; mt < 2; ++mt)
#pragma unroll
      for (int nt = 0; nt < 3; ++nt) {
        int jx = nt * 16 + l15;
        if (jx < 40) {
          int co0 = co_base + mt * 16;
          int cb = (2 * co0);
          *(u16x4*)(DX + jx * 256 + (cb ^ ((jx & 15) << 4))) = sx[mt][nt];
          if (t0 == 0 && jx == 4) {
#pragma unroll
            for (int rr = 0; rr < 4; ++rr)
              *(u16x4*)(DX + rr * 256 + (cb ^ ((rr & 15) << 4))) = sx[mt][nt];
          }
          if (t0 == Tn - TT && jx == 35) {
#pragma unroll
            for (int rr = 36; rr < 40; ++rr)
              *(u16x4*)(DX + rr * 256 + (cb ^ ((rr & 15) << 4))) = sx[mt][nt];
          }
        }
      }
  }
  __syncthreads();  // B5

  // ---- phase B conv1: G0 on xot (S0), G1 on xet (S1) ----
  {
    f32x4 acc1[2][3];
    conv_mfma<3>(grp ? S1 : S0, W1B, B1B, wv4, lg, l15, acc1);
    __syncthreads();  // B6: xet/xot tile reads complete
    write_mid_leaky<3>(grp ? S0 : S2, acc1, wv4, lg, l15);  // midC->S2, midD->S0
  }
  __syncthreads();  // B7

  // ---- phase B conv2 + final combine + store ----
  {
    f32x4 acc2[2][2];
    conv_mfma<2>(grp ? S0 : S2, W2B, B2B, wv4, lg, l15, acc2);
    float* outb = dst + ((size_t)(2 * p + grp) * SEGc + (size_t)b * NC) * Tn;
    const float* XF = grp ? XOF : XEF;
#pragma unroll
    for (int mt = 0; mt < 2; ++mt)
#pragma unroll
      for (int nt = 0; nt < 2; ++nt) {
        int tl = nt * 16 + l15;
        int co0 = co_base + mt * 16;
        const float* xrow = XF + (tl + 4) * 130 + co0;
#pragma unroll
        for (int r = 0; r < 4; ++r) {
          float tv = ftanh(acc2[mt][nt][r]);
          float res = grp ? (xrow[r] - tv) : (xrow[r] + tv);
          outb[(size_t)(co0 + r) * Tn + t0 + tl] = res;
        }
      }
  }
}

// ---------------- final projection + denorm (gathers leaf layout) ----------------
__global__ void final_kernel(const float* __restrict__ dect, const float* __restrict__ xt,
                             const float* __restrict__ projw, const float* __restrict__ means,
                             const float* __restrict__ stdev, float* __restrict__ out) {
  int b = blockIdx.x, p = blockIdx.y;
  int tid = threadIdx.x;
  const float* w = projw + (size_t)(1024 + p) * 1024;
  const float* x0 = xt + (size_t)b * NC * NL;
  float a[3] = {0.f, 0.f, 0.f};
  for (int l = tid; l < 1024; l += 256) {
    float wv = w[l];
    int rl = l & 7;
    int pb = ((rl & 1) << 2) | (rl & 2) | (rl >> 2);
    int br = (l >> 3) & 1;
    int t = l >> 4;
    const float* dl = dect + ((size_t)(2 * pb + br) * NB + b) * NC * 64 + t;
#pragma unroll
    for (int cc = 0; cc < 3; ++cc)
      a[cc] += wv * (dl[(size_t)cc * 64] + x0[(size_t)cc * NL + l]);
  }
  __shared__ float red[3][256];
  for (int cc = 0; cc < 3; ++cc) red[cc][tid] = a[cc];
  __syncthreads();
  for (int off = 128; off > 0; off >>= 1) {
    if (tid < off) {
      red[0][tid] += red[0][tid + off];
      red[1][tid] += red[1][tid + off];
      red[2][tid] += red[2][tid + off];
    }
    __syncthreads();
  }
  if (tid < 3) {
    out[((size_t)b * NP + p) * 3 + tid] = red[tid][0] * stdev[b * NC + tid] + means[b * NC + tid];
  }
}

}  // namespace

extern "C" void kernel_launch(void* const* d_in, const int* in_sizes, int n_in,
                              void* d_out, int out_size, void* d_ws, size_t ws_size,
                              hipStream_t stream) {
  (void)in_sizes; (void)n_in; (void)out_size; (void)ws_size;
  const float* x_enc = (const float*)d_in[0];
  const float* mask  = (const float*)d_in[1];
  const float* fc1_w = (const float*)d_in[2];
  const float* fc2_w = (const float*)d_in[3];
  const float* ln_g  = (const float*)d_in[4];
  const float* ln_b  = (const float*)d_in[5];
  const float* w1    = (const float*)d_in[6];
  const float* b1    = (const float*)d_in[7];
  const float* w2    = (const float*)d_in[8];
  const float* b2    = (const float*)d_in[9];
  const float* projw = (const float*)d_in[10];
  float* out = (float*)d_out;
  float* ws = (float*)d_ws;

  float* means = ws + 0;          // 4096
  float* stdev = ws + 4096;       // 4096
  float* x_t   = ws + 139264;     // 4,194,304  (B,C,L) fp32, depth-0 parent
  float* freq  = ws + 4333568;    // 4,194,304  lr fp32 -> depth-2 out
  float* IN1   = ws + 8527872;    // 4,194,304  hid_bf -> depth-0 out -> leaf out (dect)
  float* IN2   = ws + 12722176;   // 4,194,304  fc w bf16 -> depth-1 out
  float* xetr  = ws + 16916480;   // freq_bf (bf16)
  float* wp1f  = ws + 21110784;   // stats partials -> packed conv w1 bf16
  float* wp2f  = ws + 23568384;   // packed conv w2 bf16
  float* dect = IN1;
  float* stats_part = wp1f;
  u16* freq_bf = (u16*)xetr;
  u16* hid_bf  = (u16*)IN1;
  u16* fc1w_bf = (u16*)IN2;
  u16* fc2w_bf = (u16*)(IN2 + 1048576);
  u16* wp1 = (u16*)wp1f;
  u16* wp2 = (u16*)wp2f;

  stats1<<<dim3(NB, 16), 256, 0, stream>>>(x_enc, mask, stats_part);
  stats2<<<NB, 128, 0, stream>>>(stats_part, means, stdev);
  norm_transpose<<<dim3(NB, NL / 32, NC / 32), dim3(32, 8), 0, stream>>>(x_enc, mask, means, stdev, x_t);
  haar_kernel<<<NB * NC, 256, 0, stream>>>(x_t, freq_bf);

  cvt_bf16<<<2048, 256, 0, stream>>>(fc1_w, fc1w_bf, 524288);
  cvt_bf16<<<2048, 256, 0, stream>>>(fc2_w, fc2w_bf, 524288);
  pack_w<<<3840, 256, 0, stream>>>(w1, wp1);
  pack_w<<<3840, 256, 0, stream>>>(w2, wp2);

  gemm_mfma<0><<<dim3(32, 32), 256, 0, stream>>>(freq_bf, fc1w_bf, hid_bf, nullptr, 4096, 2048, 1024);
  gemm_mfma<1><<<dim3(16, 32), 256, 0, stream>>>(hid_bf, fc2w_bf, nullptr, freq, 4096, 1024, 2048);

  ln_combine<<<4096, 256, 0, stream>>>(freq, x_t, ln_g, ln_b);

  // tree: 4 fused launches; depth-buffers: x_t -> IN1 -> IN2 -> freq -> IN1(dect)
  float* dbuf[5] = {x_t, IN1, IN2, freq, IN1};
  for (int d = 0; d < 4; ++d) {
    int Tn = 512 >> d;
    dim3 grid(NB, Tn / TT, 1 << d);
    fused_cil<<<grid, 512, 0, stream>>>(dbuf[d], dbuf[d + 1], wp1, wp2, b1, b2, d, Tn);
  }

  final_kernel<<<dim3(NB, NP), 256, 0, stream>>>(dect, x_t, projw, means, stdev, out);
}

// Round 9
// 488.291 us; speedup vs baseline: 1.3548x; 1.0294x over previous
//
#include <hip/hip_runtime.h>

namespace {

constexpr int NB = 32, NL = 1024, NC = 128, NP = 96, KW = 5;
constexpr float INV_SQRT2 = 0.70710678118654752440f;
constexpr size_t SEG = (size_t)NB * NC;   // 4096
constexpr int CT = 64;                    // output columns per conv block

typedef unsigned short u16;
typedef __attribute__((ext_vector_type(4))) u16 u16x4;
typedef __attribute__((ext_vector_type(8))) u16 u16x8;
typedef __attribute__((ext_vector_type(8))) short short8;
typedef __attribute__((ext_vector_type(4))) float f32x4;

__device__ inline u16 f2bf(float f) {
  unsigned u = __float_as_uint(f);
  u += 0x7fff + ((u >> 16) & 1);
  return (u16)(u >> 16);
}

__device__ inline float ftanh(float x) {
  float e = __expf(2.f * x);
  return 1.f - 2.f / (e + 1.f);
}

// ---------------- stats stage 1 ----------------
__global__ void stats1(const float* __restrict__ x, const float* __restrict__ mask,
                       float* __restrict__ part) {
  int b = blockIdx.x, s = blockIdx.y;
  int tid = threadIdx.x;
  int c = tid & 127, lh = tid >> 7;
  const float* xb = x + (size_t)b * NL * NC;
  const float* mb = mask + (size_t)b * NL * NC;
  float s_all = 0.f, d1 = 0.f, sm = 0.f, sm2 = 0.f, cnz = 0.f;
#pragma unroll 4
  for (int i = 0; i < 32; ++i) {
    int l = s * 64 + lh + 2 * i;
    float v = xb[(size_t)l * NC + c];
    float m = mb[(size_t)l * NC + c];
    s_all += v;
    d1 += (m == 1.f) ? 1.f : 0.f;
    bool nz = (m != 0.f);
    float vm = nz ? v : 0.f;
    sm += vm;
    sm2 += vm * v;
    cnz += nz ? 1.f : 0.f;
  }
  __shared__ float red[5][256];
  red[0][tid] = s_all; red[1][tid] = d1; red[2][tid] = sm;
  red[3][tid] = sm2;   red[4][tid] = cnz;
  __syncthreads();
  if (lh == 0) {
    float* pp = part + ((size_t)(b * 16 + s) * 5) * NC + c;
#pragma unroll
    for (int q = 0; q < 5; ++q) pp[q * NC] = red[q][c] + red[q][c + 128];
  }
}

__global__ void stats2(const float* __restrict__ part, float* __restrict__ means,
                       float* __restrict__ stdev) {
  int b = blockIdx.x, c = threadIdx.x;
  float s_all = 0.f, d1 = 0.f, sm = 0.f, sm2 = 0.f, cnz = 0.f;
  for (int s = 0; s < 16; ++s) {
    const float* pp = part + ((size_t)(b * 16 + s) * 5) * NC + c;
    s_all += pp[0];
    d1    += pp[NC];
    sm    += pp[2 * NC];
    sm2   += pp[3 * NC];
    cnz   += pp[4 * NC];
  }
  float mn = s_all / d1;
  float varsum = sm2 - 2.f * mn * sm + mn * mn * cnz;
  means[b * NC + c] = mn;
  stdev[b * NC + c] = sqrtf(varsum / d1 + 1e-5f);
}

// ---------------- normalize + transpose (B,L,C) -> (B,C,L) ----------------
__global__ void norm_transpose(const float* __restrict__ x, const float* __restrict__ mask,
                               const float* __restrict__ means, const float* __restrict__ stdev,
                               float* __restrict__ xt) {
  __shared__ float tile[32][33];
  int b = blockIdx.x;
  int l0 = blockIdx.y * 32;
  int c0 = blockIdx.z * 32;
  int tx = threadIdx.x;
  int ty = threadIdx.y;
  for (int i = ty; i < 32; i += 8) {
    int l = l0 + i, c = c0 + tx;
    float v = x[((size_t)b * NL + l) * NC + c];
    float m = mask[((size_t)b * NL + l) * NC + c];
    float val = (m == 0.f) ? 0.f : (v - means[b * NC + c]);
    tile[i][tx] = val / stdev[b * NC + c];
  }
  __syncthreads();
  for (int i = ty; i < 32; i += 8) {
    xt[((size_t)b * NC + c0 + i) * NL + l0 + tx] = tile[tx][i];
  }
}

// ---------------- Haar transform per row, bf16 out ----------------
__global__ void haar_kernel(const float* __restrict__ xt, u16* __restrict__ freqb) {
  int row = blockIdx.x;
  __shared__ float h[1024], t2[512];
  const float* src = xt + (size_t)row * NL;
  u16* dst = freqb + (size_t)row * NL;
  for (int i = threadIdx.x; i < 1024; i += 256) h[i] = src[i];
  __syncthreads();
  int n = 1024;
  while (n > 1) {
    int half = n >> 1;
    for (int i = threadIdx.x; i < half; i += 256) {
      float e = h[2 * i], o = h[2 * i + 1];
      dst[half + i] = f2bf((e - o) * INV_SQRT2);
      t2[i] = (e + o) * INV_SQRT2;
    }
    __syncthreads();
    for (int i = threadIdx.x; i < half; i += 256) h[i] = t2[i];
    __syncthreads();
    n = half;
  }
  if (threadIdx.x == 0) dst[0] = f2bf(h[0]);
}

// ---------------- f32 -> bf16 ----------------
__global__ void cvt_bf16(const float* __restrict__ in, u16* __restrict__ outp, int n4) {
  int i = blockIdx.x * 256 + threadIdx.x;
  if (i < n4) {
    const float4 v = *reinterpret_cast<const float4*>(in + (size_t)i * 4);
    u16x4 o;
    o.x = f2bf(v.x); o.y = f2bf(v.y); o.z = f2bf(v.z); o.w = f2bf(v.w);
    *reinterpret_cast<u16x4*>(outp + (size_t)i * 4) = o;
  }
}

// ---------------- pack conv weights [60][co][ci][k] -> [60][k][co][ci] bf16 ----------------
__global__ void pack_w(const float* __restrict__ w, u16* __restrict__ wp) {
  int idx = blockIdx.x * 256 + threadIdx.x;
  if (idx >= 60 * 128 * 128) return;
  int ci = idx & 127;
  int co = (idx >> 7) & 127;
  int n = idx >> 14;
  const float* src = w + (size_t)idx * 5;
  size_t base = (size_t)n * (5 * 128 * 128) + (size_t)co * 128 + ci;
#pragma unroll
  for (int k = 0; k < 5; ++k)
    wp[base + (size_t)k * 16384] = f2bf(src[k]);
}

// ---------------- bf16 MFMA GEMM NT, tile 128m x 64n x 64k ----------------
template <int EPI>
__global__ __launch_bounds__(256) void gemm_mfma(const u16* __restrict__ A,
                                                 const u16* __restrict__ Bw,
                                                 u16* __restrict__ Cb, float* __restrict__ Cf,
                                                 int M, int N, int K) {
  __shared__ __align__(16) char sAB[(128 + 64) * 128];
  int m0 = blockIdx.y * 128, n0 = blockIdx.x * 64;
  int tid = threadIdx.x;
  int lane = tid & 63, wv = tid >> 6;
  int wm = (wv >> 1) * 64, wn = (wv & 1) * 32;
  int lg = lane >> 4, l15 = lane & 15;
  f32x4 zero = {0.f, 0.f, 0.f, 0.f};
  f32x4 acc[4][2];
#pragma unroll
  for (int i = 0; i < 4; ++i)
#pragma unroll
    for (int j = 0; j < 2; ++j) acc[i][j] = zero;

  for (int k0 = 0; k0 < K; k0 += 64) {
    __syncthreads();
#pragma unroll
    for (int pass = 0; pass < 6; ++pass) {
      int o = pass * 4096 + tid * 16;
      int cb = o & 127;
      int row;
      const u16* srcp;
      if (pass < 4) {
        row = o >> 7;
        srcp = A + (size_t)(m0 + row) * K + k0 + (cb >> 1);
      } else {
        int rb = (o - 16384) >> 7;
        row = 128 + rb;
        srcp = Bw + (size_t)(n0 + rb) * K + k0 + (cb >> 1);
      }
      int sw = row * 128 + (cb ^ ((row & 7) << 4));
      *(u16x8*)(sAB + sw) = *(const u16x8*)srcp;
    }
    __syncthreads();
#pragma unroll
    for (int ks = 0; ks < 2; ++ks) {
      int kb = ks * 64 + lg * 16;
      short8 a[4], bbf[2];
#pragma unroll
      for (int mt = 0; mt < 4; ++mt) {
        int rr = wm + mt * 16 + l15;
        a[mt] = *(const short8*)(sAB + rr * 128 + (kb ^ ((rr & 7) << 4)));
      }
#pragma unroll
      for (int nt = 0; nt < 2; ++nt) {
        int rr = 128 + wn + nt * 16 + l15;
        bbf[nt] = *(const short8*)(sAB + rr * 128 + (kb ^ ((rr & 7) << 4)));
      }
#pragma unroll
      for (int mt = 0; mt < 4; ++mt)
#pragma unroll
        for (int nt = 0; nt < 2; ++nt)
          acc[mt][nt] = __builtin_amdgcn_mfma_f32_16x16x32_bf16(a[mt], bbf[nt], acc[mt][nt], 0, 0, 0);
    }
  }
#pragma unroll
  for (int mt = 0; mt < 4; ++mt)
#pragma unroll
    for (int nt = 0; nt < 2; ++nt)
#pragma unroll
      for (int r = 0; r < 4; ++r) {
        int row = m0 + wm + mt * 16 + lg * 4 + r;
        int col = n0 + wn + nt * 16 + l15;
        float v = acc[mt][nt][r];
        if (EPI == 0) {
          v = v > 0.f ? v : 0.f;
          Cb[(size_t)row * N + col] = f2bf(v);
        } else {
          Cf[(size_t)row * N + col] = 1.f / (1.f + __expf(-v));
        }
      }
}

// ---------------- fused LayerNorm + combine: xt = xt * LN(lr) + pe ----------------
__global__ void ln_combine(const float* __restrict__ lr, float* __restrict__ xt,
                           const float* __restrict__ g, const float* __restrict__ bta) {
  int row = blockIdx.x;          // b*NC + c
  int c = row & 127;
  const float* p = lr + (size_t)row * 1024;
  int tid = threadIdx.x;
  float v[4];
#pragma unroll
  for (int i = 0; i < 4; ++i) v[i] = p[tid + 256 * i];
  __shared__ float red[256];
  red[tid] = v[0] + v[1] + v[2] + v[3];
  __syncthreads();
  for (int off = 128; off > 0; off >>= 1) {
    if (tid < off) red[tid] += red[tid + off];
    __syncthreads();
  }
  float mu = red[0] * (1.f / 1024.f);
  __syncthreads();
  float sq = 0.f;
#pragma unroll
  for (int i = 0; i < 4; ++i) { float d = v[i] - mu; sq += d * d; }
  red[tid] = sq;
  __syncthreads();
  for (int off = 128; off > 0; off >>= 1) {
    if (tid < off) red[tid] += red[tid + off];
    __syncthreads();
  }
  float rs = rsqrtf(red[0] * (1.f / 1024.f) + 1e-6f);
  int t = c & 63;
  float inv = __expf(-0.14619589f * (float)t);
  float* xr = xt + (size_t)row * 1024;
#pragma unroll
  for (int i = 0; i < 4; ++i) {
    int l = tid + 256 * i;
    float lrv = (v[i] - mu) * rs * g[l] + bta[l];
    float st = (float)l * inv;
    float pe = (c < 64) ? sinf(st) : cosf(st);
    xr[l] = xr[l] * lrv + pe;
  }
}

// ================= tree: 4 flat conv launches per depth =================
// mid_storage[s] = leaky(sum_k x[s-4+k] w1[k]), s in [0, Tn+4); x edge-clamped.
// z[t] = sum_k mid_storage[t+k] w2[k], t in [0, Tn).
// PHASE 0: conv1 of ccb0/ccb1 (parent -> mid). Tile row i holds x[CT*ty - 4 + i].
// PHASE 1: conv2 of ccb0/ccb1 + exp-gate (mid -> xeo_f). Tile row i = mid[CT*ty + i].
// PHASE 2: conv1 of ccb2/ccb3 (xeo_f -> mid). Tile row i holds xeo[CT*ty - 4 + i].
// PHASE 3: conv2 of ccb2/ccb3 + add/sub (mid -> child).
// Block: 512 threads = 8 waves; waves 0-3 -> pair member g=0, waves 4-7 -> g=1.
template <int PHASE>
__global__ __launch_bounds__(512) void conv_step(
    const float* __restrict__ inF, const u16* __restrict__ inB,
    u16* __restrict__ outB, float* __restrict__ outF,
    const u16* __restrict__ wp, const float* __restrict__ bp,
    int d, int Tn) {
  __shared__ __align__(16) char sm0[68 * 256];
  __shared__ __align__(16) char sm1[68 * 256];
  int b = blockIdx.x, ty = blockIdx.y, p = blockIdx.z;
  int node = 0;
  for (int i2 = d - 1; i2 >= 0; --i2) {
    int bit = (p >> i2) & 1;
    int dd = d - 1 - i2;
    node += 1 + bit * ((1 << (3 - dd)) - 1);
  }
  const int TS = Tn + 4;   // mid storage length
  int tid = threadIdx.x;
  int wq = tid >> 6;

  // ---- stage both group tiles ----
  {
    int i = tid & 63;
#pragma unroll
    for (int rep = 0; rep < 2; ++rep) {
      int ii = i + rep * 64;
      if (ii < 68) {
        int sw0 = (ii & 15) << 4;
        if (PHASE == 0) {
          int tt = CT * ty - 4 + ii;   // halo = 4 (bugfix: was -8)
          tt = tt < 0 ? 0 : (tt >= Tn ? Tn - 1 : tt);
          const float* rp = inF + ((size_t)p * SEG + (size_t)b * NC) * (size_t)(2 * Tn) + 2 * tt;
#pragma unroll
          for (int pp = 0; pp < 8; ++pp) {
            int pr = wq * 8 + pp;
            float2 v0 = *(const float2*)(rp + (size_t)(2 * pr) * (2 * Tn));
            float2 v1 = *(const float2*)(rp + (size_t)(2 * pr + 1) * (2 * Tn));
            unsigned po = (unsigned)f2bf(v0.y) | ((unsigned)f2bf(v1.y) << 16);  // xo
            unsigned pe = (unsigned)f2bf(v0.x) | ((unsigned)f2bf(v1.x) << 16);  // xe
            int sw = (4 * pr) ^ sw0;
            *(unsigned*)(sm0 + ii * 256 + sw) = po;  // ccb0 convolves xo
            *(unsigned*)(sm1 + ii * 256 + sw) = pe;  // ccb1 convolves xe
          }
        } else if (PHASE == 2) {
          int tt = CT * ty - 4 + ii;   // halo = 4 (bugfix: was -8)
          tt = tt < 0 ? 0 : (tt >= Tn ? Tn - 1 : tt);
          const float* s0 = inF + ((size_t)(p * 2 + 1) * SEG + (size_t)b * NC) * Tn + tt;  // xot
          const float* s1 = inF + ((size_t)(p * 2 + 0) * SEG + (size_t)b * NC) * Tn + tt;  // xet
#pragma unroll
          for (int pp = 0; pp < 8; ++pp) {
            int pr = wq * 8 + pp;
            unsigned a0 = (unsigned)f2bf(s0[(size_t)(2 * pr) * Tn]) |
                          ((unsigned)f2bf(s0[(size_t)(2 * pr + 1) * Tn]) << 16);
            unsigned a1 = (unsigned)f2bf(s1[(size_t)(2 * pr) * Tn]) |
                          ((unsigned)f2bf(s1[(size_t)(2 * pr + 1) * Tn]) << 16);
            int sw = (4 * pr) ^ sw0;
            *(unsigned*)(sm0 + ii * 256 + sw) = a0;  // ccb2 convolves xot
            *(unsigned*)(sm1 + ii * 256 + sw) = a1;  // ccb3 convolves xet
          }
        } else {  // PHASE 1,3: mid tiles, tile row i holds mid[CT*ty + i]
          int s = CT * ty + ii;
          const u16* m0 = inB + ((size_t)(p * 2 + 0) * SEG + (size_t)b * NC) * TS + s;
          const u16* m1 = inB + ((size_t)(p * 2 + 1) * SEG + (size_t)b * NC) * TS + s;
#pragma unroll
          for (int pp = 0; pp < 8; ++pp) {
            int pr = wq * 8 + pp;
            unsigned a0 = (unsigned)m0[(size_t)(2 * pr) * TS] |
                          ((unsigned)m0[(size_t)(2 * pr + 1) * TS] << 16);
            unsigned a1 = (unsigned)m1[(size_t)(2 * pr) * TS] |
                          ((unsigned)m1[(size_t)(2 * pr + 1) * TS] << 16);
            int sw = (4 * pr) ^ sw0;
            *(unsigned*)(sm0 + ii * 256 + sw) = a0;
            *(unsigned*)(sm1 + ii * 256 + sw) = a1;
          }
        }
      }
    }
  }
  __syncthreads();

  int lane = tid & 63, wv = tid >> 6;
  int g = wv >> 2, wv4 = wv & 3;
  int lg = lane >> 4, l15 = lane & 15;
  int co_base = wv4 * 32 + lg * 4;
  int widx = node * 4 + (PHASE >= 2 ? 2 : 0) + g;
  const u16* W = wp + (size_t)widx * (5 * 128 * 128);
  const float* Bp = bp + (size_t)widx * 128;
  const char* Sb = g ? sm1 : sm0;

  f32x4 acc[2][4];
#pragma unroll
  for (int mt = 0; mt < 2; ++mt) {
    const f32x4 bv = *(const f32x4*)(Bp + wv4 * 32 + mt * 16 + lg * 4);
#pragma unroll
    for (int nt = 0; nt < 4; ++nt) acc[mt][nt] = bv;
  }
#pragma unroll
  for (int k = 0; k < 5; ++k) {
#pragma unroll
    for (int cig = 0; cig < 4; ++cig) {
      int ci0 = cig * 32 + lg * 8;
      short8 a[2], bb[4];
#pragma unroll
      for (int mt = 0; mt < 2; ++mt) {
        int co = wv4 * 32 + mt * 16 + l15;
        a[mt] = *(const short8*)(W + ((size_t)(k * 128 + co) * 128 + ci0));
      }
      int cbyte = 2 * ci0;
#pragma unroll
      for (int nt = 0; nt < 4; ++nt) {
        int i = nt * 16 + l15 + k;
        bb[nt] = *(const short8*)(Sb + i * 256 + (cbyte ^ ((i & 15) << 4)));
      }
#pragma unroll
      for (int mt = 0; mt < 2; ++mt)
#pragma unroll
        for (int nt = 0; nt < 4; ++nt)
          acc[mt][nt] = __builtin_amdgcn_mfma_f32_16x16x32_bf16(a[mt], bb[nt], acc[mt][nt], 0, 0, 0);
    }
  }

  // ---- epilogue ----
  if (PHASE == 0 || PHASE == 2) {
    u16* mo = outB + ((size_t)(p * 2 + g) * SEG + (size_t)b * NC) * TS;
#pragma unroll
    for (int mt = 0; mt < 2; ++mt)
#pragma unroll
      for (int nt = 0; nt < 4; ++nt) {
        int s = CT * ty + nt * 16 + l15;
        if (s < TS) {
#pragma unroll
          for (int r = 0; r < 4; ++r) {
            float v = acc[mt][nt][r];
            v = v > 0.f ? v : 0.01f * v;
            mo[(size_t)(co_base + mt * 16 + r) * TS + s] = f2bf(v);
          }
        }
      }
  } else if (PHASE == 1) {
    const float* par = inF + ((size_t)p * SEG + (size_t)b * NC) * (size_t)(2 * Tn);
    float* xo_ = outF + ((size_t)(p * 2 + g) * SEG + (size_t)b * NC) * Tn;
#pragma unroll
    for (int mt = 0; mt < 2; ++mt)
#pragma unroll
      for (int nt = 0; nt < 4; ++nt) {
        int t = CT * ty + nt * 16 + l15;
#pragma unroll
        for (int r = 0; r < 4; ++r) {
          int co = co_base + mt * 16 + r;
          float xv = par[(size_t)co * (2 * Tn) + 2 * t + g];   // g0: xe, g1: xo
          xo_[(size_t)co * Tn + t] = xv * __expf(ftanh(acc[mt][nt][r]));
        }
      }
  } else {  // PHASE 3
    const float* xf = inF + ((size_t)(p * 2 + g) * SEG + (size_t)b * NC) * Tn;  // g0: xet, g1: xot
    float* ch = outF + ((size_t)(2 * p + g) * SEG + (size_t)b * NC) * Tn;
#pragma unroll
    for (int mt = 0; mt < 2; ++mt)
#pragma unroll
      for (int nt = 0; nt < 4; ++nt) {
        int t = CT * ty + nt * 16 + l15;
#pragma unroll
        for (int r = 0; r < 4; ++r) {
          int co = co_base + mt * 16 + r;
          float cv = ftanh(acc[mt][nt][r]);
          float base = xf[(size_t)co * Tn + t];
          ch[(size_t)co * Tn + t] = g ? (base - cv) : (base + cv);
        }
      }
  }
}

// ---------------- final projection + denorm (gathers leaf layout) ----------------
__global__ void final_kernel(const float* __restrict__ dect, const float* __restrict__ xt,
                             const float* __restrict__ projw, const float* __restrict__ means,
                             const float* __restrict__ stdev, float* __restrict__ out) {
  int b = blockIdx.x, p = blockIdx.y;
  int tid = threadIdx.x;
  const float* w = projw + (size_t)(1024 + p) * 1024;
  const float* x0 = xt + (size_t)b * NC * NL;
  float a[3] = {0.f, 0.f, 0.f};
  for (int l = tid; l < 1024; l += 256) {
    float wv = w[l];
    int rl = l & 7;
    int pb = ((rl & 1) << 2) | (rl & 2) | (rl >> 2);
    int br = (l >> 3) & 1;
    int t = l >> 4;
    const float* dl = dect + ((size_t)(2 * pb + br) * NB + b) * NC * 64 + t;
#pragma unroll
    for (int cc = 0; cc < 3; ++cc)
      a[cc] += wv * (dl[(size_t)cc * 64] + x0[(size_t)cc * NL + l]);
  }
  __shared__ float red[3][256];
  for (int cc = 0; cc < 3; ++cc) red[cc][tid] = a[cc];
  __syncthreads();
  for (int off = 128; off > 0; off >>= 1) {
    if (tid < off) {
      red[0][tid] += red[0][tid + off];
      red[1][tid] += red[1][tid + off];
      red[2][tid] += red[2][tid + off];
    }
    __syncthreads();
  }
  if (tid < 3) {
    out[((size_t)b * NP + p) * 3 + tid] = red[tid][0] * stdev[b * NC + tid] + means[b * NC + tid];
  }
}

}  // namespace

extern "C" void kernel_launch(void* const* d_in, const int* in_sizes, int n_in,
                              void* d_out, int out_size, void* d_ws, size_t ws_size,
                              hipStream_t stream) {
  (void)in_sizes; (void)n_in; (void)out_size; (void)ws_size;
  const float* x_enc = (const float*)d_in[0];
  const float* mask  = (const float*)d_in[1];
  const float* fc1_w = (const float*)d_in[2];
  const float* fc2_w = (const float*)d_in[3];
  const float* ln_g  = (const float*)d_in[4];
  const float* ln_b  = (const float*)d_in[5];
  const float* w1    = (const float*)d_in[6];
  const float* b1    = (const float*)d_in[7];
  const float* w2    = (const float*)d_in[8];
  const float* b2    = (const float*)d_in[9];
  const float* projw = (const float*)d_in[10];
  float* out = (float*)d_out;
  float* ws = (float*)d_ws;

  // workspace layout (floats); total ~112.5 MB
  float* means = ws + 0;          // 4096
  float* stdev = ws + 4096;       // 4096
  float* x_t   = ws + 8192;       // 4,194,304  (B,C,L) fp32, depth-0 parent + residual
  float* freq  = ws + 4202496;    // 4,194,304  lr fp32; depth-3 parent
  float* IN1   = ws + 8396800;    // 4,194,304  hid_bf; depth-1 parent; dect
  float* IN2   = ws + 12591104;   // 4,194,304  fc weights bf16; depth-2 parent
  float* xeof  = ws + 16785408;   // 4,194,304  freq_bf early; xeo fp32 [p*2+g][B][C][Tn]
  float* wp1f  = ws + 20979712;   // 2,457,600  packed conv w1 bf16
  float* wp2f  = ws + 23437312;   // 2,457,600  packed conv w2 bf16
  float* midf  = ws + 25894912;   // 2,228,224  stats partials early; mid bf16 [p*2+g][B][C][TS]
  float* dect = IN1;
  float* stats_part = midf;
  u16* freq_bf = (u16*)xeof;
  u16* hid_bf  = (u16*)IN1;
  u16* fc1w_bf = (u16*)IN2;
  u16* fc2w_bf = (u16*)(IN2 + 1048576);
  u16* wp1 = (u16*)wp1f;
  u16* wp2 = (u16*)wp2f;
  u16* midb = (u16*)midf;

  stats1<<<dim3(NB, 16), 256, 0, stream>>>(x_enc, mask, stats_part);
  stats2<<<NB, 128, 0, stream>>>(stats_part, means, stdev);
  norm_transpose<<<dim3(NB, NL / 32, NC / 32), dim3(32, 8), 0, stream>>>(x_enc, mask, means, stdev, x_t);
  haar_kernel<<<NB * NC, 256, 0, stream>>>(x_t, freq_bf);

  cvt_bf16<<<2048, 256, 0, stream>>>(fc1_w, fc1w_bf, 524288);
  cvt_bf16<<<2048, 256, 0, stream>>>(fc2_w, fc2w_bf, 524288);
  pack_w<<<3840, 256, 0, stream>>>(w1, wp1);
  pack_w<<<3840, 256, 0, stream>>>(w2, wp2);

  gemm_mfma<0><<<dim3(32, 32), 256, 0, stream>>>(freq_bf, fc1w_bf, hid_bf, nullptr, 4096, 2048, 1024);
  gemm_mfma<1><<<dim3(16, 32), 256, 0, stream>>>(hid_bf, fc2w_bf, nullptr, freq, 4096, 1024, 2048);

  ln_combine<<<4096, 256, 0, stream>>>(freq, x_t, ln_g, ln_b);

  // tree: depth buffers x_t -> IN1 -> IN2 -> freq -> IN1(dect); 4 conv launches per depth
  float* dbuf[5] = {x_t, IN1, IN2, freq, IN1};
  for (int d = 0; d < 4; ++d) {
    int Tn = 512 >> d;
    int nsub = 1 << d;
    dim3 gA(NB, (Tn + 4 + CT - 1) / CT, nsub);   // conv1 launches (Tn+4 outputs)
    dim3 gB(NB, Tn / CT, nsub);                  // conv2 launches (Tn outputs)
    conv_step<0><<<gA, 512, 0, stream>>>(dbuf[d], nullptr, midb, nullptr, wp1, b1, d, Tn);
    conv_step<1><<<gB, 512, 0, stream>>>(dbuf[d], midb, nullptr, xeof, wp2, b2, d, Tn);
    conv_step<2><<<gA, 512, 0, stream>>>(xeof, nullptr, midb, nullptr, wp1, b1, d, Tn);
    conv_step<3><<<gB, 512, 0, stream>>>(xeof, midb, nullptr, dbuf[d + 1], wp2, b2, d, Tn);
  }

  final_kernel<<<dim3(NB, NP), 256, 0, stream>>>(dect, x_t, projw, means, stdev, out);
}